// Round 1
// baseline (1002.254 us; speedup 1.0000x reference)
//
#include <hip/hip_runtime.h>
#include <hip/hip_bf16.h>
#include <cstdint>
#include <cstddef>

#define NN 50000
#define NE 600000
#define NG 2000

// ---------------- CSR build ----------------

__global__ void count_edges_kernel(const int* __restrict__ dst, int* __restrict__ cnt, int nE) {
    int e = blockIdx.x * blockDim.x + threadIdx.x;
    if (e < nE) atomicAdd(&cnt[dst[e]], 1);
}

// single-block chunked scan: row_ptr[0..n] exclusive prefix of cnt; also fills cursor copy
__global__ __launch_bounds__(1024) void scan_kernel(const int* __restrict__ cnt,
                                                    int* __restrict__ row_ptr,
                                                    int* __restrict__ cursor, int n) {
    __shared__ int sm[1024];
    int t = threadIdx.x;
    int chunk = (n + 1023) / 1024;
    int s0 = t * chunk;
    int s1 = s0 + chunk; if (s1 > n) s1 = n;
    int sum = 0;
    for (int i = s0; i < s1; ++i) sum += cnt[i];
    sm[t] = sum;
    __syncthreads();
    for (int off = 1; off < 1024; off <<= 1) {
        int v = (t >= off) ? sm[t - off] : 0;
        __syncthreads();
        sm[t] += v;
        __syncthreads();
    }
    int excl = sm[t] - sum;
    for (int i = s0; i < s1; ++i) {
        row_ptr[i] = excl;
        cursor[i]  = excl;
        excl += cnt[i];
    }
    if (t == 1023) row_ptr[n] = sm[1023];
}

// scatter edges into CSR order; perm_w = dinv[src] (dinv computed on the fly from cnt)
__global__ void scatter_kernel(const int* __restrict__ src, const int* __restrict__ dst,
                               const int* __restrict__ cnt, int* __restrict__ cursor,
                               int* __restrict__ perm_src, float* __restrict__ perm_w, int nE) {
    int e = blockIdx.x * blockDim.x + threadIdx.x;
    if (e >= nE) return;
    int d = dst[e];
    int p = atomicAdd(&cursor[d], 1);
    int s = src[e];
    perm_src[p] = s;
    perm_w[p] = rsqrtf((float)cnt[s] + 1.0f);
}

// ---------------- GEMM: Y[nRows,N] = op(X[nRows,K]) @ W[K,N] ----------------
// op = optional per-channel BN(scale,shift)+ReLU applied on load of X.
template<int K, int N, int ROWS, int RPT, int CPT, bool BN>
__global__ __launch_bounds__(256) void gemm_kernel(const float* __restrict__ X,
                                                   const float* __restrict__ W,
                                                   const float* __restrict__ scale,
                                                   const float* __restrict__ shift,
                                                   float* __restrict__ Y, int nRows) {
    constexpr int XS = ROWS + 1;
    constexpr int COLG = N / CPT;
    static_assert((ROWS / RPT) * COLG == 256, "tiling");
    __shared__ float Ws[K * N];
    __shared__ float Xs[K * XS];
    const int tid = threadIdx.x;
    const int row0 = blockIdx.x * ROWS;

    for (int i = tid; i < K * N; i += 256) Ws[i] = W[i];
    for (int i = tid; i < ROWS * K; i += 256) {
        int r = i / K, k = i - r * K;
        int gr = row0 + r;
        float v = (gr < nRows) ? X[(size_t)gr * K + k] : 0.f;
        if (BN) v = fmaxf(fmaf(v, scale[k], shift[k]), 0.f);
        Xs[k * XS + r] = v;
    }
    __syncthreads();

    const int cg = tid % COLG;
    const int rg = tid / COLG;
    const int r0 = rg * RPT;
    const int c0 = cg * CPT;
    float acc[RPT][CPT];
#pragma unroll
    for (int i = 0; i < RPT; ++i)
#pragma unroll
        for (int j = 0; j < CPT; ++j) acc[i][j] = 0.f;

    for (int k = 0; k < K; ++k) {
        float a[RPT], b[CPT];
#pragma unroll
        for (int i = 0; i < RPT; ++i) a[i] = Xs[k * XS + r0 + i];
#pragma unroll
        for (int j = 0; j < CPT; ++j) b[j] = Ws[k * N + c0 + j];
#pragma unroll
        for (int i = 0; i < RPT; ++i)
#pragma unroll
            for (int j = 0; j < CPT; ++j) acc[i][j] = fmaf(a[i], b[j], acc[i][j]);
    }
#pragma unroll
    for (int i = 0; i < RPT; ++i) {
        int gr = row0 + r0 + i;
        if (gr < nRows) {
#pragma unroll
            for (int j = 0; j < CPT; ++j) Y[(size_t)gr * N + c0 + j] = acc[i][j];
        }
    }
}

// ---------------- Aggregation: one wave per dst node ----------------
template<int C>
__global__ __launch_bounds__(256) void agg_kernel(const float* __restrict__ h,
                                                  const int* __restrict__ row_ptr,
                                                  const int* __restrict__ perm_src,
                                                  const float* __restrict__ perm_w,
                                                  const int* __restrict__ cnt,
                                                  float* __restrict__ out, int nNodes) {
    constexpr int V = C / 64;
    int wave = blockIdx.x * 4 + (threadIdx.x >> 6);
    int lane = threadIdx.x & 63;
    if (wave >= nNodes) return;
    const int d = wave;
    const float di = rsqrtf((float)cnt[d] + 1.0f);
    const int p0 = row_ptr[d], p1 = row_ptr[d + 1];
    float acc[V];
#pragma unroll
    for (int v = 0; v < V; ++v) acc[v] = 0.f;
    for (int p = p0; p < p1; ++p) {
        int s = perm_src[p];
        float w = perm_w[p] * di;
        const float* hp = h + (size_t)s * C + lane * V;
#pragma unroll
        for (int v = 0; v < V; ++v) acc[v] = fmaf(w, hp[v], acc[v]);
    }
    float idg = di * di;  // 1/deg self-loop weight
    const float* hd = h + (size_t)d * C + lane * V;
#pragma unroll
    for (int v = 0; v < V; ++v) acc[v] = fmaf(idg, hd[v], acc[v]);
    float* op = out + (size_t)d * C + lane * V;
#pragma unroll
    for (int v = 0; v < V; ++v) op[v] = acc[v];
}

// ---------------- BatchNorm stats (sum, sumsq per channel) ----------------
template<int C>
__global__ __launch_bounds__(256) void bn_stats_kernel(const float* __restrict__ x, int n,
                                                       float* __restrict__ sums) {
    constexpr int RP = 256 / C;
    __shared__ float ls[256], ls2[256];
    int c = threadIdx.x % C;
    int sub = threadIdx.x / C;
    float s = 0.f, s2 = 0.f;
    for (int r = blockIdx.x * RP + sub; r < n; r += gridDim.x * RP) {
        float v = x[(size_t)r * C + c];
        s += v; s2 += v * v;
    }
    ls[threadIdx.x] = s; ls2[threadIdx.x] = s2;
    __syncthreads();
    if (sub == 0) {
#pragma unroll
        for (int k = 1; k < RP; ++k) { s += ls[k * C + c]; s2 += ls2[k * C + c]; }
        atomicAdd(&sums[c], s);
        atomicAdd(&sums[C + c], s2);
    }
}

__global__ void bn_finalize_kernel(const float* __restrict__ sums, int C, float invN,
                                   const float* __restrict__ gamma, const float* __restrict__ beta,
                                   float* __restrict__ scale, float* __restrict__ shift) {
    int c = blockIdx.x * blockDim.x + threadIdx.x;
    if (c >= C) return;
    float m = sums[c] * invN;
    float var = sums[C + c] * invN - m * m;
    float sc = gamma[c] * rsqrtf(var + 1e-5f);
    scale[c] = sc;
    shift[c] = beta[c] - m * sc;
}

// ---------------- Mean pool per graph (batch sorted; binary search) ----------------
__global__ __launch_bounds__(64) void pool_kernel(const float* __restrict__ x,
                                                  const float* __restrict__ scale,
                                                  const float* __restrict__ shift,
                                                  const int* __restrict__ batch,
                                                  float* __restrict__ Hmean, int colBase, int n) {
    int g = blockIdx.x;
    int c = threadIdx.x;
    int lo = 0, hi = n;
    while (lo < hi) { int mid = (lo + hi) >> 1; if (batch[mid] < g) lo = mid + 1; else hi = mid; }
    int start = lo;
    hi = n;
    while (lo < hi) { int mid = (lo + hi) >> 1; if (batch[mid] <= g) lo = mid + 1; else hi = mid; }
    int end = lo;
    float s = 0.f;
    float sc = scale[c], sh = shift[c];
    for (int r = start; r < end; ++r)
        s += fmaxf(fmaf(x[(size_t)r * 64 + c], sc, sh), 0.f);
    float cf = (float)(end - start);
    Hmean[(size_t)g * 128 + colBase + c] = s / fmaxf(cf, 1.f);
}

// ---------------- Head ----------------
__global__ __launch_bounds__(64) void head_gemm1_kernel(const float* __restrict__ H,
                                                        const float* __restrict__ Wf1,
                                                        float* __restrict__ T) {
    __shared__ float row[128];
    int g = blockIdx.x;
    int c = threadIdx.x;
    row[c] = H[(size_t)g * 128 + c];
    row[c + 64] = H[(size_t)g * 128 + 64 + c];
    __syncthreads();
    float acc = 0.f;
#pragma unroll 8
    for (int k = 0; k < 128; ++k) acc = fmaf(row[k], Wf1[k * 64 + c], acc);
    T[(size_t)g * 64 + c] = acc;  // bf1 cancels under BN
}

__global__ __launch_bounds__(64) void head_final_kernel(const float* __restrict__ T,
                                                        const float* __restrict__ scale,
                                                        const float* __restrict__ shift,
                                                        const float* __restrict__ Wf2,
                                                        const float* __restrict__ bf2,
                                                        float* __restrict__ out) {
    int g = blockIdx.x;
    int c = threadIdx.x;
    float v = fmaxf(fmaf(T[(size_t)g * 64 + c], scale[c], shift[c]), 0.f) * Wf2[c];
#pragma unroll
    for (int off = 32; off > 0; off >>= 1) v += __shfl_down(v, off, 64);
    if (c == 0) out[g] = v + bf2[0];
}

// ---------------- Host orchestration ----------------

static inline size_t alignup(size_t x) { return (x + 255) & ~(size_t)255; }

extern "C" void kernel_launch(void* const* d_in, const int* in_sizes, int n_in,
                              void* d_out, int out_size, void* d_ws, size_t ws_size,
                              hipStream_t stream) {
    const float* xc  = (const float*)d_in[0];
    const float* xs  = (const float*)d_in[1];
    const int*   eic = (const int*)d_in[2];
    const int*   eis = (const int*)d_in[3];
    const int*   batch = (const int*)d_in[4];
    const float* W1c = (const float*)d_in[5];
    const float* g1c = (const float*)d_in[7];
    const float* be1c = (const float*)d_in[8];
    const float* W2c = (const float*)d_in[9];
    const float* g2c = (const float*)d_in[11];
    const float* be2c = (const float*)d_in[12];
    const float* W1s = (const float*)d_in[13];
    const float* g1s = (const float*)d_in[15];
    const float* be1s = (const float*)d_in[16];
    const float* W2s = (const float*)d_in[17];
    const float* g2s = (const float*)d_in[19];
    const float* be2s = (const float*)d_in[20];
    const float* Wf1 = (const float*)d_in[21];
    const float* gf1 = (const float*)d_in[23];
    const float* bef1 = (const float*)d_in[24];
    const float* Wf2 = (const float*)d_in[25];
    const float* bf2 = (const float*)d_in[26];
    float* out = (float*)d_out;

    char* ws = (char*)d_ws;
    size_t off = 0;
    auto alloc = [&](size_t bytes) { char* p = ws + off; off += alignup(bytes); return p; };

    int*   cnt      = (int*)alloc(NN * 4);
    int*   row_ptr  = (int*)alloc((NN + 1) * 4);
    int*   cursor   = (int*)alloc(NN * 4);
    int*   perm_src = (int*)alloc(NE * 4);
    float* perm_w   = (float*)alloc(NE * 4);
    float* bufA     = (float*)alloc((size_t)NN * 128 * 4);  // h1, then h2
    float* bufB     = (float*)alloc((size_t)NN * 128 * 4);  // agg1, then agg2
    float* sums     = (float*)alloc(256 * 4);
    float* bnscale  = (float*)alloc(128 * 4);
    float* bnshift  = (float*)alloc(128 * 4);
    float* Hmean    = (float*)alloc((size_t)NG * 128 * 4);
    float* T        = (float*)alloc((size_t)NG * 64 * 4);

    const float invN = 1.0f / (float)NN;

    auto run_branch = [&](const float* x, const int* ei,
                          const float* W1, const float* g1, const float* be1,
                          const float* W2, const float* g2, const float* be2,
                          int colBase) {
        const int* src = ei;
        const int* dst = ei + NE;
        // CSR build
        hipMemsetAsync(cnt, 0, NN * 4, stream);
        count_edges_kernel<<<(NE + 255) / 256, 256, 0, stream>>>(dst, cnt, NE);
        scan_kernel<<<1, 1024, 0, stream>>>(cnt, row_ptr, cursor, NN);
        scatter_kernel<<<(NE + 255) / 256, 256, 0, stream>>>(src, dst, cnt, cursor,
                                                             perm_src, perm_w, NE);
        // layer 1: h1 = x @ W1
        gemm_kernel<64, 128, 64, 4, 8, false><<<(NN + 63) / 64, 256, 0, stream>>>(
            x, W1, nullptr, nullptr, bufA, NN);
        agg_kernel<128><<<(NN + 3) / 4, 256, 0, stream>>>(bufA, row_ptr, perm_src, perm_w,
                                                          cnt, bufB, NN);
        hipMemsetAsync(sums, 0, 256 * 4, stream);
        bn_stats_kernel<128><<<256, 256, 0, stream>>>(bufB, NN, sums);
        bn_finalize_kernel<<<1, 128, 0, stream>>>(sums, 128, invN, g1, be1, bnscale, bnshift);
        // layer 2: h2 = bnrelu(agg1) @ W2  (BN+ReLU fused into load)
        gemm_kernel<128, 64, 32, 2, 4, true><<<(NN + 31) / 32, 256, 0, stream>>>(
            bufB, W2, bnscale, bnshift, bufA, NN);
        agg_kernel<64><<<(NN + 3) / 4, 256, 0, stream>>>(bufA, row_ptr, perm_src, perm_w,
                                                         cnt, bufB, NN);
        hipMemsetAsync(sums, 0, 256 * 4, stream);
        bn_stats_kernel<64><<<256, 256, 0, stream>>>(bufB, NN, sums);
        bn_finalize_kernel<<<1, 64, 0, stream>>>(sums, 64, invN, g2, be2, bnscale, bnshift);
        // pool (BN+ReLU fused)
        pool_kernel<<<NG, 64, 0, stream>>>(bufB, bnscale, bnshift, batch, Hmean, colBase, NN);
    };

    run_branch(xc, eic, W1c, g1c, be1c, W2c, g2c, be2c, 0);
    run_branch(xs, eis, W1s, g1s, be1s, W2s, g2s, be2s, 64);

    // head
    head_gemm1_kernel<<<NG, 64, 0, stream>>>(Hmean, Wf1, T);
    hipMemsetAsync(sums, 0, 256 * 4, stream);
    bn_stats_kernel<64><<<32, 256, 0, stream>>>(T, NG, sums);
    bn_finalize_kernel<<<1, 64, 0, stream>>>(sums, 64, 1.0f / (float)NG, gf1, bef1,
                                             bnscale, bnshift);
    head_final_kernel<<<NG, 64, 0, stream>>>(T, bnscale, bnshift, Wf2, bf2, out);
}

// Round 2
// 804.305 us; speedup vs baseline: 1.2461x; 1.2461x over previous
//
#include <hip/hip_runtime.h>
#include <hip/hip_bf16.h>
#include <cstdint>
#include <cstddef>

#define NN 50000
#define NE 600000
#define NG 2000
#define SCAN_TILE 1024

// ---------------- CSR build ----------------

__global__ void count_edges_kernel(const int* __restrict__ dst, int* __restrict__ cnt, int nE) {
    int e = blockIdx.x * blockDim.x + threadIdx.x;
    if (e < nE) atomicAdd(&cnt[dst[e]], 1);
}

// pass 1: per-block tile sums (tile = 1024 elements, 256 threads x 4)
__global__ __launch_bounds__(256) void scan_pass1(const int* __restrict__ cnt,
                                                  int* __restrict__ blk, int n) {
    __shared__ int sm[256];
    int t = threadIdx.x;
    int base = blockIdx.x * SCAN_TILE + t * 4;
    int s = 0;
#pragma unroll
    for (int j = 0; j < 4; ++j) { int i = base + j; if (i < n) s += cnt[i]; }
    sm[t] = s;
    __syncthreads();
    for (int off = 128; off > 0; off >>= 1) {
        if (t < off) sm[t] += sm[t + off];
        __syncthreads();
    }
    if (t == 0) blk[blockIdx.x] = sm[0];
}

// pass 2: each block recomputes its base from blk[], scans its tile, writes row_ptr+cursor
__global__ __launch_bounds__(256) void scan_pass2(const int* __restrict__ cnt,
                                                  const int* __restrict__ blk,
                                                  int* __restrict__ row_ptr,
                                                  int* __restrict__ cursor, int n) {
    __shared__ int sm[256];
    __shared__ int sbase;
    int t = threadIdx.x;
    // base = sum of blk[i] for i < blockIdx.x
    int b = 0;
    for (int i = t; i < blockIdx.x; i += 256) b += blk[i];
    sm[t] = b;
    __syncthreads();
    for (int off = 128; off > 0; off >>= 1) {
        if (t < off) sm[t] += sm[t + off];
        __syncthreads();
    }
    if (t == 0) sbase = sm[0];
    __syncthreads();
    int base = sbase;
    __syncthreads();

    int i0 = blockIdx.x * SCAN_TILE + t * 4;
    int v[4];
    int s = 0;
#pragma unroll
    for (int j = 0; j < 4; ++j) { int i = i0 + j; v[j] = (i < n) ? cnt[i] : 0; s += v[j]; }
    sm[t] = s;
    __syncthreads();
    // inclusive Hillis-Steele scan over per-thread sums
    for (int off = 1; off < 256; off <<= 1) {
        int tmp = (t >= off) ? sm[t - off] : 0;
        __syncthreads();
        sm[t] += tmp;
        __syncthreads();
    }
    int run = base + sm[t] - s;  // exclusive prefix for this thread's first element
#pragma unroll
    for (int j = 0; j < 4; ++j) {
        int i = i0 + j;
        if (i < n) {
            row_ptr[i] = run;
            cursor[i] = run;
            run += v[j];
            if (i == n - 1) row_ptr[n] = run;
        }
    }
}

// scatter edges into CSR order; perm_w = dinv[src]
__global__ void scatter_kernel(const int* __restrict__ src, const int* __restrict__ dst,
                               const int* __restrict__ cnt, int* __restrict__ cursor,
                               int* __restrict__ perm_src, float* __restrict__ perm_w, int nE) {
    int e = blockIdx.x * blockDim.x + threadIdx.x;
    if (e >= nE) return;
    int d = dst[e];
    int p = atomicAdd(&cursor[d], 1);
    int s = src[e];
    perm_src[p] = s;
    perm_w[p] = rsqrtf((float)cnt[s] + 1.0f);
}

// ---------------- GEMM: Y[nRows,N] = op(X[nRows,K]) @ W[K,N] ----------------
template<int K, int N, int ROWS, int RPT, int CPT, bool BN>
__global__ __launch_bounds__(256) void gemm_kernel(const float* __restrict__ X,
                                                   const float* __restrict__ W,
                                                   const float* __restrict__ scale,
                                                   const float* __restrict__ shift,
                                                   float* __restrict__ Y, int nRows) {
    constexpr int XS = ROWS + 1;
    constexpr int COLG = N / CPT;
    static_assert((ROWS / RPT) * COLG == 256, "tiling");
    __shared__ float Ws[K * N];
    __shared__ float Xs[K * XS];
    const int tid = threadIdx.x;
    const int row0 = blockIdx.x * ROWS;

    for (int i = tid; i < K * N; i += 256) Ws[i] = W[i];
    for (int i = tid; i < ROWS * K; i += 256) {
        int r = i / K, k = i - r * K;
        int gr = row0 + r;
        float v = (gr < nRows) ? X[(size_t)gr * K + k] : 0.f;
        if (BN) v = fmaxf(fmaf(v, scale[k], shift[k]), 0.f);
        Xs[k * XS + r] = v;
    }
    __syncthreads();

    const int cg = tid % COLG;
    const int rg = tid / COLG;
    const int r0 = rg * RPT;
    const int c0 = cg * CPT;
    float acc[RPT][CPT];
#pragma unroll
    for (int i = 0; i < RPT; ++i)
#pragma unroll
        for (int j = 0; j < CPT; ++j) acc[i][j] = 0.f;

    for (int k = 0; k < K; ++k) {
        float a[RPT], b[CPT];
#pragma unroll
        for (int i = 0; i < RPT; ++i) a[i] = Xs[k * XS + r0 + i];
#pragma unroll
        for (int j = 0; j < CPT; ++j) b[j] = Ws[k * N + c0 + j];
#pragma unroll
        for (int i = 0; i < RPT; ++i)
#pragma unroll
            for (int j = 0; j < CPT; ++j) acc[i][j] = fmaf(a[i], b[j], acc[i][j]);
    }
#pragma unroll
    for (int i = 0; i < RPT; ++i) {
        int gr = row0 + r0 + i;
        if (gr < nRows) {
#pragma unroll
            for (int j = 0; j < CPT; ++j) Y[(size_t)gr * N + c0 + j] = acc[i][j];
        }
    }
}

// ---------------- Aggregation: one wave per dst node ----------------
template<int C>
__global__ __launch_bounds__(256) void agg_kernel(const float* __restrict__ h,
                                                  const int* __restrict__ row_ptr,
                                                  const int* __restrict__ perm_src,
                                                  const float* __restrict__ perm_w,
                                                  const int* __restrict__ cnt,
                                                  float* __restrict__ out, int nNodes) {
    constexpr int V = C / 64;
    int wave = blockIdx.x * 4 + (threadIdx.x >> 6);
    int lane = threadIdx.x & 63;
    if (wave >= nNodes) return;
    const int d = wave;
    const float di = rsqrtf((float)cnt[d] + 1.0f);
    const int p0 = row_ptr[d], p1 = row_ptr[d + 1];
    float acc[V];
#pragma unroll
    for (int v = 0; v < V; ++v) acc[v] = 0.f;
    for (int p = p0; p < p1; ++p) {
        int s = perm_src[p];
        float w = perm_w[p] * di;
        const float* hp = h + (size_t)s * C + lane * V;
#pragma unroll
        for (int v = 0; v < V; ++v) acc[v] = fmaf(w, hp[v], acc[v]);
    }
    float idg = di * di;  // 1/deg self-loop weight
    const float* hd = h + (size_t)d * C + lane * V;
#pragma unroll
    for (int v = 0; v < V; ++v) acc[v] = fmaf(idg, hd[v], acc[v]);
    float* op = out + (size_t)d * C + lane * V;
#pragma unroll
    for (int v = 0; v < V; ++v) op[v] = acc[v];
}

// ---------------- BatchNorm stats (sum, sumsq per channel) ----------------
template<int C>
__global__ __launch_bounds__(256) void bn_stats_kernel(const float* __restrict__ x, int n,
                                                       float* __restrict__ sums) {
    constexpr int RP = 256 / C;
    __shared__ float ls[256], ls2[256];
    int c = threadIdx.x % C;
    int sub = threadIdx.x / C;
    float s = 0.f, s2 = 0.f;
    for (int r = blockIdx.x * RP + sub; r < n; r += gridDim.x * RP) {
        float v = x[(size_t)r * C + c];
        s += v; s2 += v * v;
    }
    ls[threadIdx.x] = s; ls2[threadIdx.x] = s2;
    __syncthreads();
    if (sub == 0) {
#pragma unroll
        for (int k = 1; k < RP; ++k) { s += ls[k * C + c]; s2 += ls2[k * C + c]; }
        atomicAdd(&sums[c], s);
        atomicAdd(&sums[C + c], s2);
    }
}

__global__ void bn_finalize_kernel(const float* __restrict__ sums, int C, float invN,
                                   const float* __restrict__ gamma, const float* __restrict__ beta,
                                   float* __restrict__ scale, float* __restrict__ shift) {
    int c = blockIdx.x * blockDim.x + threadIdx.x;
    if (c >= C) return;
    float m = sums[c] * invN;
    float var = sums[C + c] * invN - m * m;
    float sc = gamma[c] * rsqrtf(var + 1e-5f);
    scale[c] = sc;
    shift[c] = beta[c] - m * sc;
}

// ---------------- Mean pool per graph (batch sorted; binary search) ----------------
__global__ __launch_bounds__(64) void pool_kernel(const float* __restrict__ x,
                                                  const float* __restrict__ scale,
                                                  const float* __restrict__ shift,
                                                  const int* __restrict__ batch,
                                                  float* __restrict__ Hmean, int colBase, int n) {
    int g = blockIdx.x;
    int c = threadIdx.x;
    int lo = 0, hi = n;
    while (lo < hi) { int mid = (lo + hi) >> 1; if (batch[mid] < g) lo = mid + 1; else hi = mid; }
    int start = lo;
    hi = n;
    while (lo < hi) { int mid = (lo + hi) >> 1; if (batch[mid] <= g) lo = mid + 1; else hi = mid; }
    int end = lo;
    float s = 0.f;
    float sc = scale[c], sh = shift[c];
    for (int r = start; r < end; ++r)
        s += fmaxf(fmaf(x[(size_t)r * 64 + c], sc, sh), 0.f);
    float cf = (float)(end - start);
    Hmean[(size_t)g * 128 + colBase + c] = s / fmaxf(cf, 1.f);
}

// ---------------- Head ----------------
__global__ __launch_bounds__(64) void head_gemm1_kernel(const float* __restrict__ H,
                                                        const float* __restrict__ Wf1,
                                                        float* __restrict__ T) {
    __shared__ float row[128];
    int g = blockIdx.x;
    int c = threadIdx.x;
    row[c] = H[(size_t)g * 128 + c];
    row[c + 64] = H[(size_t)g * 128 + 64 + c];
    __syncthreads();
    float acc = 0.f;
#pragma unroll 8
    for (int k = 0; k < 128; ++k) acc = fmaf(row[k], Wf1[k * 64 + c], acc);
    T[(size_t)g * 64 + c] = acc;  // bf1 cancels under BN
}

__global__ __launch_bounds__(64) void head_final_kernel(const float* __restrict__ T,
                                                        const float* __restrict__ scale,
                                                        const float* __restrict__ shift,
                                                        const float* __restrict__ Wf2,
                                                        const float* __restrict__ bf2,
                                                        float* __restrict__ out) {
    int g = blockIdx.x;
    int c = threadIdx.x;
    float v = fmaxf(fmaf(T[(size_t)g * 64 + c], scale[c], shift[c]), 0.f) * Wf2[c];
#pragma unroll
    for (int off = 32; off > 0; off >>= 1) v += __shfl_down(v, off, 64);
    if (c == 0) out[g] = v + bf2[0];
}

// ---------------- Host orchestration ----------------

static inline size_t alignup(size_t x) { return (x + 255) & ~(size_t)255; }

extern "C" void kernel_launch(void* const* d_in, const int* in_sizes, int n_in,
                              void* d_out, int out_size, void* d_ws, size_t ws_size,
                              hipStream_t stream) {
    const float* xc  = (const float*)d_in[0];
    const float* xs  = (const float*)d_in[1];
    const int*   eic = (const int*)d_in[2];
    const int*   eis = (const int*)d_in[3];
    const int*   batch = (const int*)d_in[4];
    const float* W1c = (const float*)d_in[5];
    const float* g1c = (const float*)d_in[7];
    const float* be1c = (const float*)d_in[8];
    const float* W2c = (const float*)d_in[9];
    const float* g2c = (const float*)d_in[11];
    const float* be2c = (const float*)d_in[12];
    const float* W1s = (const float*)d_in[13];
    const float* g1s = (const float*)d_in[15];
    const float* be1s = (const float*)d_in[16];
    const float* W2s = (const float*)d_in[17];
    const float* g2s = (const float*)d_in[19];
    const float* be2s = (const float*)d_in[20];
    const float* Wf1 = (const float*)d_in[21];
    const float* gf1 = (const float*)d_in[23];
    const float* bef1 = (const float*)d_in[24];
    const float* Wf2 = (const float*)d_in[25];
    const float* bf2 = (const float*)d_in[26];
    float* out = (float*)d_out;

    char* ws = (char*)d_ws;
    size_t off = 0;
    auto alloc = [&](size_t bytes) { char* p = ws + off; off += alignup(bytes); return p; };

    int*   cnt      = (int*)alloc(NN * 4);
    int*   row_ptr  = (int*)alloc((NN + 1) * 4);
    int*   cursor   = (int*)alloc(NN * 4);
    int*   blk      = (int*)alloc(((NN + SCAN_TILE - 1) / SCAN_TILE) * 4);
    int*   perm_src = (int*)alloc(NE * 4);
    float* perm_w   = (float*)alloc(NE * 4);
    float* bufA     = (float*)alloc((size_t)NN * 128 * 4);  // h1, then h2
    float* bufB     = (float*)alloc((size_t)NN * 128 * 4);  // agg1, then agg2
    float* sums     = (float*)alloc(256 * 4);
    float* bnscale  = (float*)alloc(128 * 4);
    float* bnshift  = (float*)alloc(128 * 4);
    float* Hmean    = (float*)alloc((size_t)NG * 128 * 4);
    float* T        = (float*)alloc((size_t)NG * 64 * 4);

    const float invN = 1.0f / (float)NN;
    const int nBlkScan = (NN + SCAN_TILE - 1) / SCAN_TILE;

    auto run_branch = [&](const float* x, const int* ei,
                          const float* W1, const float* g1, const float* be1,
                          const float* W2, const float* g2, const float* be2,
                          int colBase) {
        const int* src = ei;
        const int* dst = ei + NE;
        // CSR build
        hipMemsetAsync(cnt, 0, NN * 4, stream);
        count_edges_kernel<<<(NE + 255) / 256, 256, 0, stream>>>(dst, cnt, NE);
        scan_pass1<<<nBlkScan, 256, 0, stream>>>(cnt, blk, NN);
        scan_pass2<<<nBlkScan, 256, 0, stream>>>(cnt, blk, row_ptr, cursor, NN);
        scatter_kernel<<<(NE + 255) / 256, 256, 0, stream>>>(src, dst, cnt, cursor,
                                                             perm_src, perm_w, NE);
        // layer 1: h1 = x @ W1
        gemm_kernel<64, 128, 64, 4, 8, false><<<(NN + 63) / 64, 256, 0, stream>>>(
            x, W1, nullptr, nullptr, bufA, NN);
        agg_kernel<128><<<(NN + 3) / 4, 256, 0, stream>>>(bufA, row_ptr, perm_src, perm_w,
                                                          cnt, bufB, NN);
        hipMemsetAsync(sums, 0, 256 * 4, stream);
        bn_stats_kernel<128><<<256, 256, 0, stream>>>(bufB, NN, sums);
        bn_finalize_kernel<<<1, 128, 0, stream>>>(sums, 128, invN, g1, be1, bnscale, bnshift);
        // layer 2: h2 = bnrelu(agg1) @ W2  (BN+ReLU fused into load)
        gemm_kernel<128, 64, 32, 2, 4, true><<<(NN + 31) / 32, 256, 0, stream>>>(
            bufB, W2, bnscale, bnshift, bufA, NN);
        agg_kernel<64><<<(NN + 3) / 4, 256, 0, stream>>>(bufA, row_ptr, perm_src, perm_w,
                                                         cnt, bufB, NN);
        hipMemsetAsync(sums, 0, 256 * 4, stream);
        bn_stats_kernel<64><<<256, 256, 0, stream>>>(bufB, NN, sums);
        bn_finalize_kernel<<<1, 64, 0, stream>>>(sums, 64, invN, g2, be2, bnscale, bnshift);
        // pool (BN+ReLU fused)
        pool_kernel<<<NG, 64, 0, stream>>>(bufB, bnscale, bnshift, batch, Hmean, colBase, NN);
    };

    run_branch(xc, eic, W1c, g1c, be1c, W2c, g2c, be2c, 0);
    run_branch(xs, eis, W1s, g1s, be1s, W2s, g2s, be2s, 64);

    // head
    head_gemm1_kernel<<<NG, 64, 0, stream>>>(Hmean, Wf1, T);
    hipMemsetAsync(sums, 0, 256 * 4, stream);
    bn_stats_kernel<64><<<32, 256, 0, stream>>>(T, NG, sums);
    bn_finalize_kernel<<<1, 64, 0, stream>>>(sums, 64, 1.0f / (float)NG, gf1, bef1,
                                             bnscale, bnshift);
    head_final_kernel<<<NG, 64, 0, stream>>>(T, bnscale, bnshift, Wf2, bf2, out);
}

// Round 3
// 668.098 us; speedup vs baseline: 1.5002x; 1.2039x over previous
//
#include <hip/hip_runtime.h>
#include <hip/hip_bf16.h>
#include <cstdint>
#include <cstddef>

#define NN 50000
#define NE 600000
#define NG 2000
#define SCAN_TILE 1024
#define NBLK ((NN + SCAN_TILE - 1) / SCAN_TILE)

// ---------------- CSR build (batched over 2 branches via blockIdx.y) ----------------

__global__ void count2_kernel(const int* __restrict__ d0, const int* __restrict__ d1,
                              int* __restrict__ cnt, int nE) {
    int b = blockIdx.y;
    const int* dst = b ? d1 : d0;
    int e = blockIdx.x * blockDim.x + threadIdx.x;
    if (e < nE) atomicAdd(&cnt[b * NN + dst[e]], 1);
}

__global__ __launch_bounds__(256) void scan_pass1(const int* __restrict__ cnt,
                                                  int* __restrict__ blk, int n) {
    __shared__ int sm[256];
    const int* cb = cnt + blockIdx.y * NN;
    int* bb = blk + blockIdx.y * NBLK;
    int t = threadIdx.x;
    int base = blockIdx.x * SCAN_TILE + t * 4;
    int s = 0;
#pragma unroll
    for (int j = 0; j < 4; ++j) { int i = base + j; if (i < n) s += cb[i]; }
    sm[t] = s;
    __syncthreads();
    for (int off = 128; off > 0; off >>= 1) {
        if (t < off) sm[t] += sm[t + off];
        __syncthreads();
    }
    if (t == 0) bb[blockIdx.x] = sm[0];
}

__global__ __launch_bounds__(256) void scan_pass2(const int* __restrict__ cnt,
                                                  const int* __restrict__ blk,
                                                  int* __restrict__ row_ptr,
                                                  int* __restrict__ cursor, int n) {
    __shared__ int sm[256];
    __shared__ int sbase;
    const int* cb = cnt + blockIdx.y * NN;
    const int* bb = blk + blockIdx.y * NBLK;
    int* rp = row_ptr + blockIdx.y * (NN + 1);
    int* cu = cursor + blockIdx.y * NN;
    int t = threadIdx.x;
    int b = 0;
    for (int i = t; i < blockIdx.x; i += 256) b += bb[i];
    sm[t] = b;
    __syncthreads();
    for (int off = 128; off > 0; off >>= 1) {
        if (t < off) sm[t] += sm[t + off];
        __syncthreads();
    }
    if (t == 0) sbase = sm[0];
    __syncthreads();
    int base = sbase;
    __syncthreads();

    int i0 = blockIdx.x * SCAN_TILE + t * 4;
    int v[4];
    int s = 0;
#pragma unroll
    for (int j = 0; j < 4; ++j) { int i = i0 + j; v[j] = (i < n) ? cb[i] : 0; s += v[j]; }
    sm[t] = s;
    __syncthreads();
    for (int off = 1; off < 256; off <<= 1) {
        int tmp = (t >= off) ? sm[t - off] : 0;
        __syncthreads();
        sm[t] += tmp;
        __syncthreads();
    }
    int run = base + sm[t] - s;
#pragma unroll
    for (int j = 0; j < 4; ++j) {
        int i = i0 + j;
        if (i < n) {
            rp[i] = run;
            cu[i] = run;
            run += v[j];
            if (i == n - 1) rp[n] = run;
        }
    }
}

__global__ void scatter2_kernel(const int* __restrict__ s0, const int* __restrict__ d0,
                                const int* __restrict__ s1, const int* __restrict__ d1,
                                const int* __restrict__ cnt, int* __restrict__ cursor,
                                int* __restrict__ perm_src, float* __restrict__ perm_w, int nE) {
    int b = blockIdx.y;
    const int* src = b ? s1 : s0;
    const int* dst = b ? d1 : d0;
    int e = blockIdx.x * blockDim.x + threadIdx.x;
    if (e >= nE) return;
    int d = dst[e];
    int p = atomicAdd(&cursor[b * NN + d], 1);
    int s = src[e];
    perm_src[(size_t)b * NE + p] = s;
    perm_w[(size_t)b * NE + p] = rsqrtf((float)cnt[b * NN + s] + 1.0f);
}

// ---------------- Batched GEMM: Y[b][nRows,N] = op(X[b][nRows,K]) @ W[b][K,N] ----------------
template<int K, int N, int ROWS, int RPT, int CPT, bool BN>
__global__ __launch_bounds__(256) void gemm2_kernel(const float* __restrict__ X0,
                                                    const float* __restrict__ X1,
                                                    const float* __restrict__ W0,
                                                    const float* __restrict__ W1,
                                                    const float* __restrict__ scale,
                                                    const float* __restrict__ shift,
                                                    float* __restrict__ Y0,
                                                    float* __restrict__ Y1, int nRows) {
    constexpr int XS = ROWS + 1;
    constexpr int COLG = N / CPT;
    static_assert((ROWS / RPT) * COLG == 256, "tiling");
    __shared__ float Ws[K * N];
    __shared__ float Xs[K * XS];
    const int b = blockIdx.y;
    const float* X = b ? X1 : X0;
    const float* W = b ? W1 : W0;
    const float* sc = scale + b * K;
    const float* sh = shift + b * K;
    float* Y = b ? Y1 : Y0;
    const int tid = threadIdx.x;
    const int row0 = blockIdx.x * ROWS;

    for (int i = tid; i < K * N; i += 256) Ws[i] = W[i];
    for (int i = tid; i < ROWS * K; i += 256) {
        int r = i / K, k = i - r * K;
        int gr = row0 + r;
        float v = (gr < nRows) ? X[(size_t)gr * K + k] : 0.f;
        if (BN) v = fmaxf(fmaf(v, sc[k], sh[k]), 0.f);
        Xs[k * XS + r] = v;
    }
    __syncthreads();

    const int cg = tid % COLG;
    const int rg = tid / COLG;
    const int r0 = rg * RPT;
    const int c0 = cg * CPT;
    float acc[RPT][CPT];
#pragma unroll
    for (int i = 0; i < RPT; ++i)
#pragma unroll
        for (int j = 0; j < CPT; ++j) acc[i][j] = 0.f;

    for (int k = 0; k < K; ++k) {
        float a[RPT], bb[CPT];
#pragma unroll
        for (int i = 0; i < RPT; ++i) a[i] = Xs[k * XS + r0 + i];
#pragma unroll
        for (int j = 0; j < CPT; ++j) bb[j] = Ws[k * N + c0 + j];
#pragma unroll
        for (int i = 0; i < RPT; ++i)
#pragma unroll
            for (int j = 0; j < CPT; ++j) acc[i][j] = fmaf(a[i], bb[j], acc[i][j]);
    }
#pragma unroll
    for (int i = 0; i < RPT; ++i) {
        int gr = row0 + r0 + i;
        if (gr < nRows) {
#pragma unroll
            for (int j = 0; j < CPT; ++j) Y[(size_t)gr * N + c0 + j] = acc[i][j];
        }
    }
}

// ---------------- Batched aggregation: one wave per dst node, 2 branches ----------------
template<int C>
__global__ __launch_bounds__(256) void agg2_kernel(const float* __restrict__ h0,
                                                   const float* __restrict__ h1,
                                                   const int* __restrict__ row_ptr,
                                                   const int* __restrict__ perm_src,
                                                   const float* __restrict__ perm_w,
                                                   const int* __restrict__ cnt,
                                                   float* __restrict__ out, int nNodes) {
    constexpr int V = C / 64;
    int b = blockIdx.y;
    const float* h = b ? h1 : h0;
    const int* rp = row_ptr + b * (NN + 1);
    const int* ps = perm_src + (size_t)b * NE;
    const float* pw = perm_w + (size_t)b * NE;
    const int* cc = cnt + b * NN;
    float* ob = out + (size_t)b * nNodes * C;

    int wave = blockIdx.x * 4 + (threadIdx.x >> 6);
    int lane = threadIdx.x & 63;
    if (wave >= nNodes) return;
    const int d = wave;
    const float di = rsqrtf((float)cc[d] + 1.0f);
    const int p0 = rp[d], p1 = rp[d + 1];
    float acc[V];
#pragma unroll
    for (int v = 0; v < V; ++v) acc[v] = 0.f;
    for (int p = p0; p < p1; ++p) {
        int s = ps[p];
        float w = pw[p] * di;
        const float* hp = h + (size_t)s * C + lane * V;
#pragma unroll
        for (int v = 0; v < V; ++v) acc[v] = fmaf(w, hp[v], acc[v]);
    }
    float idg = di * di;
    const float* hd = h + (size_t)d * C + lane * V;
#pragma unroll
    for (int v = 0; v < V; ++v) acc[v] = fmaf(idg, hd[v], acc[v]);
    float* op = ob + (size_t)d * C + lane * V;
#pragma unroll
    for (int v = 0; v < V; ++v) op[v] = acc[v];
}

// ---------------- BatchNorm stats (batched) ----------------
template<int C>
__global__ __launch_bounds__(256) void bn_stats2_kernel(const float* __restrict__ x,
                                                        size_t xstride, int n,
                                                        float* __restrict__ sums) {
    constexpr int RP = 256 / C;
    __shared__ float ls[256], ls2[256];
    const float* xb = x + blockIdx.y * xstride;
    float* sb = sums + blockIdx.y * (2 * C);
    int c = threadIdx.x % C;
    int sub = threadIdx.x / C;
    float s = 0.f, s2 = 0.f;
    for (int r = blockIdx.x * RP + sub; r < n; r += gridDim.x * RP) {
        float v = xb[(size_t)r * C + c];
        s += v; s2 += v * v;
    }
    ls[threadIdx.x] = s; ls2[threadIdx.x] = s2;
    __syncthreads();
    if (sub == 0) {
#pragma unroll
        for (int k = 1; k < RP; ++k) { s += ls[k * C + c]; s2 += ls2[k * C + c]; }
        atomicAdd(&sb[c], s);
        atomicAdd(&sb[C + c], s2);
    }
}

__global__ void bn_finalize2_kernel(const float* __restrict__ sums, int C, float invN,
                                    const float* __restrict__ g0, const float* __restrict__ g1,
                                    const float* __restrict__ b0, const float* __restrict__ b1,
                                    float* __restrict__ scale, float* __restrict__ shift) {
    int b = blockIdx.y;
    int c = threadIdx.x;
    if (c >= C) return;
    const float* sm = sums + b * 2 * C;
    const float* gamma = b ? g1 : g0;
    const float* beta = b ? b1 : b0;
    float m = sm[c] * invN;
    float var = sm[C + c] * invN - m * m;
    float sc = gamma[c] * rsqrtf(var + 1e-5f);
    scale[b * C + c] = sc;
    shift[b * C + c] = beta[c] - m * sc;
}

// single (for head)
__global__ void bn_finalize_kernel(const float* __restrict__ sums, int C, float invN,
                                   const float* __restrict__ gamma, const float* __restrict__ beta,
                                   float* __restrict__ scale, float* __restrict__ shift) {
    int c = blockIdx.x * blockDim.x + threadIdx.x;
    if (c >= C) return;
    float m = sums[c] * invN;
    float var = sums[C + c] * invN - m * m;
    float sc = gamma[c] * rsqrtf(var + 1e-5f);
    scale[c] = sc;
    shift[c] = beta[c] - m * sc;
}

// ---------------- Mean pool per graph (batched; batch sorted; binary search) ----------------
__global__ __launch_bounds__(64) void pool2_kernel(const float* __restrict__ x,
                                                   const float* __restrict__ scale,
                                                   const float* __restrict__ shift,
                                                   const int* __restrict__ batch,
                                                   float* __restrict__ Hmean, int n) {
    int b = blockIdx.y;
    const float* xb = x + (size_t)b * NN * 64;
    int g = blockIdx.x;
    int c = threadIdx.x;
    int lo = 0, hi = n;
    while (lo < hi) { int mid = (lo + hi) >> 1; if (batch[mid] < g) lo = mid + 1; else hi = mid; }
    int start = lo;
    hi = n;
    while (lo < hi) { int mid = (lo + hi) >> 1; if (batch[mid] <= g) lo = mid + 1; else hi = mid; }
    int end = lo;
    float s = 0.f;
    float sc = scale[b * 64 + c], sh = shift[b * 64 + c];
    for (int r = start; r < end; ++r)
        s += fmaxf(fmaf(xb[(size_t)r * 64 + c], sc, sh), 0.f);
    float cf = (float)(end - start);
    Hmean[(size_t)g * 128 + b * 64 + c] = s / fmaxf(cf, 1.f);
}

// ---------------- Head ----------------
__global__ __launch_bounds__(64) void head_gemm1_kernel(const float* __restrict__ H,
                                                        const float* __restrict__ Wf1,
                                                        float* __restrict__ T) {
    __shared__ float row[128];
    int g = blockIdx.x;
    int c = threadIdx.x;
    row[c] = H[(size_t)g * 128 + c];
    row[c + 64] = H[(size_t)g * 128 + 64 + c];
    __syncthreads();
    float acc = 0.f;
#pragma unroll 8
    for (int k = 0; k < 128; ++k) acc = fmaf(row[k], Wf1[k * 64 + c], acc);
    T[(size_t)g * 64 + c] = acc;
}

__global__ __launch_bounds__(64) void head_final_kernel(const float* __restrict__ T,
                                                        const float* __restrict__ scale,
                                                        const float* __restrict__ shift,
                                                        const float* __restrict__ Wf2,
                                                        const float* __restrict__ bf2,
                                                        float* __restrict__ out) {
    int g = blockIdx.x;
    int c = threadIdx.x;
    float v = fmaxf(fmaf(T[(size_t)g * 64 + c], scale[c], shift[c]), 0.f) * Wf2[c];
#pragma unroll
    for (int off = 32; off > 0; off >>= 1) v += __shfl_down(v, off, 64);
    if (c == 0) out[g] = v + bf2[0];
}

// single-branch bn_stats for head
template<int C>
__global__ __launch_bounds__(256) void bn_stats_kernel(const float* __restrict__ x, int n,
                                                       float* __restrict__ sums) {
    constexpr int RP = 256 / C;
    __shared__ float ls[256], ls2[256];
    int c = threadIdx.x % C;
    int sub = threadIdx.x / C;
    float s = 0.f, s2 = 0.f;
    for (int r = blockIdx.x * RP + sub; r < n; r += gridDim.x * RP) {
        float v = x[(size_t)r * C + c];
        s += v; s2 += v * v;
    }
    ls[threadIdx.x] = s; ls2[threadIdx.x] = s2;
    __syncthreads();
    if (sub == 0) {
#pragma unroll
        for (int k = 1; k < RP; ++k) { s += ls[k * C + c]; s2 += ls2[k * C + c]; }
        atomicAdd(&sums[c], s);
        atomicAdd(&sums[C + c], s2);
    }
}

// ---------------- Host orchestration ----------------

static inline size_t alignup(size_t x) { return (x + 255) & ~(size_t)255; }

extern "C" void kernel_launch(void* const* d_in, const int* in_sizes, int n_in,
                              void* d_out, int out_size, void* d_ws, size_t ws_size,
                              hipStream_t stream) {
    const float* xc  = (const float*)d_in[0];
    const float* xs  = (const float*)d_in[1];
    const int*   eic = (const int*)d_in[2];
    const int*   eis = (const int*)d_in[3];
    const int*   batch = (const int*)d_in[4];
    const float* W1c = (const float*)d_in[5];
    const float* g1c = (const float*)d_in[7];
    const float* be1c = (const float*)d_in[8];
    const float* W2c = (const float*)d_in[9];
    const float* g2c = (const float*)d_in[11];
    const float* be2c = (const float*)d_in[12];
    const float* W1s = (const float*)d_in[13];
    const float* g1s = (const float*)d_in[15];
    const float* be1s = (const float*)d_in[16];
    const float* W2s = (const float*)d_in[17];
    const float* g2s = (const float*)d_in[19];
    const float* be2s = (const float*)d_in[20];
    const float* Wf1 = (const float*)d_in[21];
    const float* gf1 = (const float*)d_in[23];
    const float* bef1 = (const float*)d_in[24];
    const float* Wf2 = (const float*)d_in[25];
    const float* bf2 = (const float*)d_in[26];
    float* out = (float*)d_out;

    char* ws = (char*)d_ws;
    size_t off = 0;
    auto alloc = [&](size_t bytes) { char* p = ws + off; off += alignup(bytes); return p; };

    int*   cnt      = (int*)alloc(2 * NN * 4);
    int*   row_ptr  = (int*)alloc(2 * (NN + 1) * 4);
    int*   cursor   = (int*)alloc(2 * NN * 4);
    int*   blk      = (int*)alloc(2 * NBLK * 4);
    int*   perm_src = (int*)alloc((size_t)2 * NE * 4);
    float* perm_w   = (float*)alloc((size_t)2 * NE * 4);
    float* aggx     = (float*)alloc((size_t)2 * NN * 64 * 4);   // layer1 agg(x); reused as layer2 agg out
    float* h1buf    = (float*)alloc((size_t)2 * NN * 128 * 4);  // GCN1 output
    float* h2buf    = (float*)alloc((size_t)2 * NN * 64 * 4);   // gemm2 output (pre-agg)
    float* sums     = (float*)alloc(2 * 256 * 4);
    float* bnscale  = (float*)alloc(2 * 128 * 4);
    float* bnshift  = (float*)alloc(2 * 128 * 4);
    float* Hmean    = (float*)alloc((size_t)NG * 128 * 4);
    float* T        = (float*)alloc((size_t)NG * 64 * 4);

    const float invN = 1.0f / (float)NN;
    const dim3 eg((NE + 255) / 256, 2);

    // ---- CSR build for both branches ----
    hipMemsetAsync(cnt, 0, 2 * NN * 4, stream);
    count2_kernel<<<eg, 256, 0, stream>>>(eic + NE, eis + NE, cnt, NE);
    scan_pass1<<<dim3(NBLK, 2), 256, 0, stream>>>(cnt, blk, NN);
    scan_pass2<<<dim3(NBLK, 2), 256, 0, stream>>>(cnt, blk, row_ptr, cursor, NN);
    scatter2_kernel<<<eg, 256, 0, stream>>>(eic, eic + NE, eis, eis + NE,
                                            cnt, cursor, perm_src, perm_w, NE);

    // ---- Layer 1: aggregate raw x (64ch), then GEMM 64->128 (A(XW)=(AX)W) ----
    agg2_kernel<64><<<dim3((NN + 3) / 4, 2), 256, 0, stream>>>(
        xc, xs, row_ptr, perm_src, perm_w, cnt, aggx, NN);
    gemm2_kernel<64, 128, 64, 4, 8, false><<<dim3((NN + 63) / 64, 2), 256, 0, stream>>>(
        aggx, aggx + (size_t)NN * 64, W1c, W1s, nullptr, nullptr,
        h1buf, h1buf + (size_t)NN * 128, NN);
    hipMemsetAsync(sums, 0, 2 * 256 * 4, stream);
    bn_stats2_kernel<128><<<dim3(256, 2), 256, 0, stream>>>(h1buf, (size_t)NN * 128, NN, sums);
    bn_finalize2_kernel<<<dim3(1, 2), 128, 0, stream>>>(sums, 128, invN,
                                                        g1c, g1s, be1c, be1s, bnscale, bnshift);

    // ---- Layer 2: BN+ReLU fused into GEMM load, 128->64, then aggregate ----
    gemm2_kernel<128, 64, 32, 2, 4, true><<<dim3((NN + 31) / 32, 2), 256, 0, stream>>>(
        h1buf, h1buf + (size_t)NN * 128, W2c, W2s, bnscale, bnshift,
        h2buf, h2buf + (size_t)NN * 64, NN);
    agg2_kernel<64><<<dim3((NN + 3) / 4, 2), 256, 0, stream>>>(
        h2buf, h2buf + (size_t)NN * 64, row_ptr, perm_src, perm_w, cnt, aggx, NN);
    hipMemsetAsync(sums, 0, 2 * 256 * 4, stream);
    bn_stats2_kernel<64><<<dim3(256, 2), 256, 0, stream>>>(aggx, (size_t)NN * 64, NN, sums);
    bn_finalize2_kernel<<<dim3(1, 2), 64, 0, stream>>>(sums, 64, invN,
                                                       g2c, g2s, be2c, be2s, bnscale, bnshift);

    // ---- Pool (BN+ReLU fused) ----
    pool2_kernel<<<dim3(NG, 2), 64, 0, stream>>>(aggx, bnscale, bnshift, batch, Hmean, NN);

    // ---- Head ----
    head_gemm1_kernel<<<NG, 64, 0, stream>>>(Hmean, Wf1, T);
    hipMemsetAsync(sums, 0, 256 * 4, stream);
    bn_stats_kernel<64><<<32, 256, 0, stream>>>(T, NG, sums);
    bn_finalize_kernel<<<1, 64, 0, stream>>>(sums, 64, 1.0f / (float)NG, gf1, bef1,
                                             bnscale, bnshift);
    head_final_kernel<<<NG, 64, 0, stream>>>(T, bnscale, bnshift, Wf2, bf2, out);
}

// Round 4
// 523.606 us; speedup vs baseline: 1.9141x; 1.2760x over previous
//
#include <hip/hip_runtime.h>
#include <hip/hip_bf16.h>
#include <cstdint>
#include <cstddef>

#define NN 50000
#define NE 600000
#define NG 2000
#define SCAN_TILE 1024
#define NBLK ((NN + SCAN_TILE - 1) / SCAN_TILE)
#define SLOTS 16

// ---------------- CSR build (batched over 2 branches via blockIdx.y) ----------------

__global__ void count2_kernel(const int* __restrict__ d0, const int* __restrict__ d1,
                              int* __restrict__ cnt, int nE) {
    int b = blockIdx.y;
    const int* dst = b ? d1 : d0;
    int e = blockIdx.x * blockDim.x + threadIdx.x;
    if (e < nE) atomicAdd(&cnt[b * NN + dst[e]], 1);
}

__global__ __launch_bounds__(256) void scan_pass1(const int* __restrict__ cnt,
                                                  int* __restrict__ blk, int n) {
    __shared__ int sm[256];
    const int* cb = cnt + blockIdx.y * NN;
    int* bb = blk + blockIdx.y * NBLK;
    int t = threadIdx.x;
    int base = blockIdx.x * SCAN_TILE + t * 4;
    int s = 0;
#pragma unroll
    for (int j = 0; j < 4; ++j) { int i = base + j; if (i < n) s += cb[i]; }
    sm[t] = s;
    __syncthreads();
    for (int off = 128; off > 0; off >>= 1) {
        if (t < off) sm[t] += sm[t + off];
        __syncthreads();
    }
    if (t == 0) bb[blockIdx.x] = sm[0];
}

__global__ __launch_bounds__(256) void scan_pass2(const int* __restrict__ cnt,
                                                  const int* __restrict__ blk,
                                                  int* __restrict__ row_ptr,
                                                  int* __restrict__ cursor, int n) {
    __shared__ int sm[256];
    __shared__ int sbase;
    const int* cb = cnt + blockIdx.y * NN;
    const int* bb = blk + blockIdx.y * NBLK;
    int* rp = row_ptr + blockIdx.y * (NN + 1);
    int* cu = cursor + blockIdx.y * NN;
    int t = threadIdx.x;
    int b = 0;
    for (int i = t; i < blockIdx.x; i += 256) b += bb[i];
    sm[t] = b;
    __syncthreads();
    for (int off = 128; off > 0; off >>= 1) {
        if (t < off) sm[t] += sm[t + off];
        __syncthreads();
    }
    if (t == 0) sbase = sm[0];
    __syncthreads();
    int base = sbase;
    __syncthreads();

    int i0 = blockIdx.x * SCAN_TILE + t * 4;
    int v[4];
    int s = 0;
#pragma unroll
    for (int j = 0; j < 4; ++j) { int i = i0 + j; v[j] = (i < n) ? cb[i] : 0; s += v[j]; }
    sm[t] = s;
    __syncthreads();
    for (int off = 1; off < 256; off <<= 1) {
        int tmp = (t >= off) ? sm[t - off] : 0;
        __syncthreads();
        sm[t] += tmp;
        __syncthreads();
    }
    int run = base + sm[t] - s;
#pragma unroll
    for (int j = 0; j < 4; ++j) {
        int i = i0 + j;
        if (i < n) {
            rp[i] = run;
            cu[i] = run;
            run += v[j];
            if (i == n - 1) rp[n] = run;
        }
    }
}

__global__ void scatter2_kernel(const int* __restrict__ s0, const int* __restrict__ d0,
                                const int* __restrict__ s1, const int* __restrict__ d1,
                                const int* __restrict__ cnt, int* __restrict__ cursor,
                                int* __restrict__ perm_src, float* __restrict__ perm_w, int nE) {
    int b = blockIdx.y;
    const int* src = b ? s1 : s0;
    const int* dst = b ? d1 : d0;
    int e = blockIdx.x * blockDim.x + threadIdx.x;
    if (e >= nE) return;
    int d = dst[e];
    int p = atomicAdd(&cursor[b * NN + d], 1);
    int s = src[e];
    perm_src[(size_t)b * NE + p] = s;
    perm_w[(size_t)b * NE + p] = rsqrtf((float)cnt[b * NN + s] + 1.0f);
}

// ---------------- Batched GEMM: Y[b][nRows,N] = op(X[b][nRows,K]) @ W[b][K,N] ----------------
// STATS: accumulate per-channel sum/sumsq of Y into sums (slot-striped atomics).
template<int K, int N, int ROWS, int RPT, int CPT, bool BN, bool STATS>
__global__ __launch_bounds__(256) void gemm2_kernel(const float* __restrict__ X0,
                                                    const float* __restrict__ X1,
                                                    const float* __restrict__ W0,
                                                    const float* __restrict__ W1,
                                                    const float* __restrict__ scale,
                                                    const float* __restrict__ shift,
                                                    float* __restrict__ Y0,
                                                    float* __restrict__ Y1,
                                                    float* __restrict__ sums, int nRows) {
    constexpr int XS = ROWS + 1;
    constexpr int COLG = N / CPT;
    static_assert((ROWS / RPT) * COLG == 256, "tiling");
    __shared__ float Ws[K * N];
    __shared__ float Xs[K * XS];
    const int b = blockIdx.y;
    const float* X = b ? X1 : X0;
    const float* W = b ? W1 : W0;
    const float* sc = scale + b * K;
    const float* sh = shift + b * K;
    float* Y = b ? Y1 : Y0;
    const int tid = threadIdx.x;
    const int row0 = blockIdx.x * ROWS;

    for (int i = tid; i < K * N; i += 256) Ws[i] = W[i];
    for (int i = tid; i < ROWS * K; i += 256) {
        int r = i / K, k = i - r * K;
        int gr = row0 + r;
        float v = (gr < nRows) ? X[(size_t)gr * K + k] : 0.f;
        if (BN) v = fmaxf(fmaf(v, sc[k], sh[k]), 0.f);
        Xs[k * XS + r] = v;
    }
    __syncthreads();

    const int cg = tid % COLG;
    const int rg = tid / COLG;
    const int r0 = rg * RPT;
    const int c0 = cg * CPT;
    float acc[RPT][CPT];
#pragma unroll
    for (int i = 0; i < RPT; ++i)
#pragma unroll
        for (int j = 0; j < CPT; ++j) acc[i][j] = 0.f;

    for (int k = 0; k < K; ++k) {
        float a[RPT], bb[CPT];
#pragma unroll
        for (int i = 0; i < RPT; ++i) a[i] = Xs[k * XS + r0 + i];
#pragma unroll
        for (int j = 0; j < CPT; ++j) bb[j] = Ws[k * N + c0 + j];
#pragma unroll
        for (int i = 0; i < RPT; ++i)
#pragma unroll
            for (int j = 0; j < CPT; ++j) acc[i][j] = fmaf(a[i], bb[j], acc[i][j]);
    }
#pragma unroll
    for (int i = 0; i < RPT; ++i) {
        int gr = row0 + r0 + i;
        if (gr < nRows) {
#pragma unroll
            for (int j = 0; j < CPT; ++j) Y[(size_t)gr * N + c0 + j] = acc[i][j];
        }
    }
    if constexpr (STATS) {
        // padded rows produce acc==0 exactly (BN==false path) -> contribute nothing
        __shared__ float ls[N], ls2[N];
        for (int i = tid; i < N; i += 256) { ls[i] = 0.f; ls2[i] = 0.f; }
        __syncthreads();
#pragma unroll
        for (int j = 0; j < CPT; ++j) {
            float sj = 0.f, s2j = 0.f;
#pragma unroll
            for (int i = 0; i < RPT; ++i) { float v = acc[i][j]; sj += v; s2j = fmaf(v, v, s2j); }
            atomicAdd(&ls[c0 + j], sj);
            atomicAdd(&ls2[c0 + j], s2j);
        }
        __syncthreads();
        int slot = blockIdx.x & (SLOTS - 1);
        float* sb = sums + ((size_t)(blockIdx.y * SLOTS + slot) * 2) * N;
        for (int i = tid; i < N; i += 256) {
            atomicAdd(&sb[i], ls[i]);
            atomicAdd(&sb[N + i], ls2[i]);
        }
    }
}

// ---------------- Batched aggregation (C=64): one wave per dst node, unroll-8 ----------------
template<bool STATS>
__global__ __launch_bounds__(256) void agg2_kernel(const float* __restrict__ h0,
                                                   const float* __restrict__ h1,
                                                   const int* __restrict__ row_ptr,
                                                   const int* __restrict__ perm_src,
                                                   const float* __restrict__ perm_w,
                                                   const int* __restrict__ cnt,
                                                   float* __restrict__ out,
                                                   float* __restrict__ sums, int nNodes) {
    const int b = blockIdx.y;
    const float* __restrict__ h = b ? h1 : h0;
    const int* rp = row_ptr + b * (NN + 1);
    const int* ps = perm_src + (size_t)b * NE;
    const float* pw = perm_w + (size_t)b * NE;
    const int* cc = cnt + b * NN;
    float* ob = out + (size_t)b * nNodes * 64;

    const int wave = blockIdx.x * 4 + (threadIdx.x >> 6);
    const int lane = threadIdx.x & 63;
    float fin = 0.f;
    const bool active = wave < nNodes;
    if (active) {
        const int d = wave;
        const float di = rsqrtf((float)cc[d] + 1.0f);
        const int p0 = rp[d], p1 = rp[d + 1];
        float a = 0.f;
        for (int p = p0; p < p1; p += 8) {
            int idx[8]; float w[8];
#pragma unroll
            for (int k = 0; k < 8; ++k) {
                bool vld = (p + k) < p1;
                int pk = vld ? (p + k) : p;   // dup of first slot: same cache line, w=0
                idx[k] = ps[pk];
                w[k] = vld ? pw[pk] : 0.f;
            }
            float v[8];
#pragma unroll
            for (int k = 0; k < 8; ++k) v[k] = h[(size_t)idx[k] * 64 + lane];
#pragma unroll
            for (int k = 0; k < 8; ++k) a = fmaf(w[k], v[k], a);
        }
        float hd = h[(size_t)d * 64 + lane];
        fin = di * fmaf(di, hd, a);   // di*(sum + di*h_d)
        ob[(size_t)d * 64 + lane] = fin;
    }
    if constexpr (STATS) {
        __shared__ float ls[256], ls2[256];
        ls[threadIdx.x] = fin;
        ls2[threadIdx.x] = fin * fin;
        __syncthreads();
        if (threadIdx.x < 64) {
            float s  = ls[threadIdx.x] + ls[threadIdx.x + 64] + ls[threadIdx.x + 128] + ls[threadIdx.x + 192];
            float s2 = ls2[threadIdx.x] + ls2[threadIdx.x + 64] + ls2[threadIdx.x + 128] + ls2[threadIdx.x + 192];
            int slot = blockIdx.x & (SLOTS - 1);
            float* sb = sums + ((size_t)(b * SLOTS + slot) * 2) * 64;
            atomicAdd(&sb[threadIdx.x], s);
            atomicAdd(&sb[64 + threadIdx.x], s2);
        }
    }
}

// ---------------- BN finalize (slot-striped sums) ----------------
__global__ void bn_finalize2_kernel(const float* __restrict__ sums, int C, float invN,
                                    const float* __restrict__ g0, const float* __restrict__ g1,
                                    const float* __restrict__ b0, const float* __restrict__ b1,
                                    float* __restrict__ scale, float* __restrict__ shift) {
    int b = blockIdx.y;
    int c = threadIdx.x;
    if (c >= C) return;
    float s = 0.f, s2 = 0.f;
    for (int k = 0; k < SLOTS; ++k) {
        const float* sb = sums + ((size_t)(b * SLOTS + k) * 2) * C;
        s += sb[c];
        s2 += sb[C + c];
    }
    const float* gamma = b ? g1 : g0;
    const float* beta = b ? b1 : b0;
    float m = s * invN;
    float var = s2 * invN - m * m;
    float sc = gamma[c] * rsqrtf(var + 1e-5f);
    scale[b * C + c] = sc;
    shift[b * C + c] = beta[c] - m * sc;
}

// single (for head)
__global__ void bn_finalize_kernel(const float* __restrict__ sums, int C, float invN,
                                   const float* __restrict__ gamma, const float* __restrict__ beta,
                                   float* __restrict__ scale, float* __restrict__ shift) {
    int c = blockIdx.x * blockDim.x + threadIdx.x;
    if (c >= C) return;
    float m = sums[c] * invN;
    float var = sums[C + c] * invN - m * m;
    float sc = gamma[c] * rsqrtf(var + 1e-5f);
    scale[c] = sc;
    shift[c] = beta[c] - m * sc;
}

// ---------------- Mean pool per graph (batched; batch sorted; binary search) ----------------
__global__ __launch_bounds__(64) void pool2_kernel(const float* __restrict__ x,
                                                   const float* __restrict__ scale,
                                                   const float* __restrict__ shift,
                                                   const int* __restrict__ batch,
                                                   float* __restrict__ Hmean, int n) {
    int b = blockIdx.y;
    const float* xb = x + (size_t)b * NN * 64;
    int g = blockIdx.x;
    int c = threadIdx.x;
    int lo = 0, hi = n;
    while (lo < hi) { int mid = (lo + hi) >> 1; if (batch[mid] < g) lo = mid + 1; else hi = mid; }
    int start = lo;
    hi = n;
    while (lo < hi) { int mid = (lo + hi) >> 1; if (batch[mid] <= g) lo = mid + 1; else hi = mid; }
    int end = lo;
    float s = 0.f;
    float sc = scale[b * 64 + c], sh = shift[b * 64 + c];
    for (int r = start; r < end; ++r)
        s += fmaxf(fmaf(xb[(size_t)r * 64 + c], sc, sh), 0.f);
    float cf = (float)(end - start);
    Hmean[(size_t)g * 128 + b * 64 + c] = s / fmaxf(cf, 1.f);
}

// ---------------- Head ----------------
__global__ __launch_bounds__(64) void head_gemm1_kernel(const float* __restrict__ H,
                                                        const float* __restrict__ Wf1,
                                                        float* __restrict__ T) {
    __shared__ float row[128];
    int g = blockIdx.x;
    int c = threadIdx.x;
    row[c] = H[(size_t)g * 128 + c];
    row[c + 64] = H[(size_t)g * 128 + 64 + c];
    __syncthreads();
    float acc = 0.f;
#pragma unroll 8
    for (int k = 0; k < 128; ++k) acc = fmaf(row[k], Wf1[k * 64 + c], acc);
    T[(size_t)g * 64 + c] = acc;
}

__global__ __launch_bounds__(64) void head_final_kernel(const float* __restrict__ T,
                                                        const float* __restrict__ scale,
                                                        const float* __restrict__ shift,
                                                        const float* __restrict__ Wf2,
                                                        const float* __restrict__ bf2,
                                                        float* __restrict__ out) {
    int g = blockIdx.x;
    int c = threadIdx.x;
    float v = fmaxf(fmaf(T[(size_t)g * 64 + c], scale[c], shift[c]), 0.f) * Wf2[c];
#pragma unroll
    for (int off = 32; off > 0; off >>= 1) v += __shfl_down(v, off, 64);
    if (c == 0) out[g] = v + bf2[0];
}

// single-branch bn_stats for head
template<int C>
__global__ __launch_bounds__(256) void bn_stats_kernel(const float* __restrict__ x, int n,
                                                       float* __restrict__ sums) {
    constexpr int RP = 256 / C;
    __shared__ float ls[256], ls2[256];
    int c = threadIdx.x % C;
    int sub = threadIdx.x / C;
    float s = 0.f, s2 = 0.f;
    for (int r = blockIdx.x * RP + sub; r < n; r += gridDim.x * RP) {
        float v = x[(size_t)r * C + c];
        s += v; s2 += v * v;
    }
    ls[threadIdx.x] = s; ls2[threadIdx.x] = s2;
    __syncthreads();
    if (sub == 0) {
#pragma unroll
        for (int k = 1; k < RP; ++k) { s += ls[k * C + c]; s2 += ls2[k * C + c]; }
        atomicAdd(&sums[c], s);
        atomicAdd(&sums[C + c], s2);
    }
}

// ---------------- Host orchestration ----------------

static inline size_t alignup(size_t x) { return (x + 255) & ~(size_t)255; }

extern "C" void kernel_launch(void* const* d_in, const int* in_sizes, int n_in,
                              void* d_out, int out_size, void* d_ws, size_t ws_size,
                              hipStream_t stream) {
    const float* xc  = (const float*)d_in[0];
    const float* xs  = (const float*)d_in[1];
    const int*   eic = (const int*)d_in[2];
    const int*   eis = (const int*)d_in[3];
    const int*   batch = (const int*)d_in[4];
    const float* W1c = (const float*)d_in[5];
    const float* g1c = (const float*)d_in[7];
    const float* be1c = (const float*)d_in[8];
    const float* W2c = (const float*)d_in[9];
    const float* g2c = (const float*)d_in[11];
    const float* be2c = (const float*)d_in[12];
    const float* W1s = (const float*)d_in[13];
    const float* g1s = (const float*)d_in[15];
    const float* be1s = (const float*)d_in[16];
    const float* W2s = (const float*)d_in[17];
    const float* g2s = (const float*)d_in[19];
    const float* be2s = (const float*)d_in[20];
    const float* Wf1 = (const float*)d_in[21];
    const float* gf1 = (const float*)d_in[23];
    const float* bef1 = (const float*)d_in[24];
    const float* Wf2 = (const float*)d_in[25];
    const float* bf2 = (const float*)d_in[26];
    float* out = (float*)d_out;

    char* ws = (char*)d_ws;
    size_t off = 0;
    auto alloc = [&](size_t bytes) { char* p = ws + off; off += alignup(bytes); return p; };

    int*   cnt      = (int*)alloc(2 * NN * 4);
    int*   row_ptr  = (int*)alloc(2 * (NN + 1) * 4);
    int*   cursor   = (int*)alloc(2 * NN * 4);
    int*   blk      = (int*)alloc(2 * NBLK * 4);
    int*   perm_src = (int*)alloc(((size_t)2 * NE + 64) * 4);
    float* perm_w   = (float*)alloc(((size_t)2 * NE + 64) * 4);
    float* aggx     = (float*)alloc((size_t)2 * NN * 64 * 4);
    float* h1buf    = (float*)alloc((size_t)2 * NN * 128 * 4);
    float* h2buf    = (float*)alloc((size_t)2 * NN * 64 * 4);
    float* sums     = (float*)alloc((size_t)2 * SLOTS * 2 * 128 * 4);  // 32 KB
    float* hsums    = (float*)alloc(128 * 4);
    float* bnscale  = (float*)alloc(2 * 128 * 4);
    float* bnshift  = (float*)alloc(2 * 128 * 4);
    float* Hmean    = (float*)alloc((size_t)NG * 128 * 4);
    float* T        = (float*)alloc((size_t)NG * 64 * 4);

    const float invN = 1.0f / (float)NN;
    const dim3 eg((NE + 255) / 256, 2);
    const size_t sumsBytes = (size_t)2 * SLOTS * 2 * 128 * 4;

    // ---- CSR build for both branches ----
    hipMemsetAsync(cnt, 0, 2 * NN * 4, stream);
    count2_kernel<<<eg, 256, 0, stream>>>(eic + NE, eis + NE, cnt, NE);
    scan_pass1<<<dim3(NBLK, 2), 256, 0, stream>>>(cnt, blk, NN);
    scan_pass2<<<dim3(NBLK, 2), 256, 0, stream>>>(cnt, blk, row_ptr, cursor, NN);
    scatter2_kernel<<<eg, 256, 0, stream>>>(eic, eic + NE, eis, eis + NE,
                                            cnt, cursor, perm_src, perm_w, NE);

    // ---- Layer 1: aggregate raw x (64ch), then GEMM 64->128 with fused BN stats ----
    agg2_kernel<false><<<dim3((NN + 3) / 4, 2), 256, 0, stream>>>(
        xc, xs, row_ptr, perm_src, perm_w, cnt, aggx, nullptr, NN);
    hipMemsetAsync(sums, 0, sumsBytes, stream);
    gemm2_kernel<64, 128, 64, 4, 8, false, true><<<dim3((NN + 63) / 64, 2), 256, 0, stream>>>(
        aggx, aggx + (size_t)NN * 64, W1c, W1s, nullptr, nullptr,
        h1buf, h1buf + (size_t)NN * 128, sums, NN);
    bn_finalize2_kernel<<<dim3(1, 2), 128, 0, stream>>>(sums, 128, invN,
                                                        g1c, g1s, be1c, be1s, bnscale, bnshift);

    // ---- Layer 2: BN+ReLU fused into GEMM load, 128->64, then aggregate w/ fused stats ----
    gemm2_kernel<128, 64, 32, 2, 4, true, false><<<dim3((NN + 31) / 32, 2), 256, 0, stream>>>(
        h1buf, h1buf + (size_t)NN * 128, W2c, W2s, bnscale, bnshift,
        h2buf, h2buf + (size_t)NN * 64, nullptr, NN);
    hipMemsetAsync(sums, 0, sumsBytes, stream);
    agg2_kernel<true><<<dim3((NN + 3) / 4, 2), 256, 0, stream>>>(
        h2buf, h2buf + (size_t)NN * 64, row_ptr, perm_src, perm_w, cnt, aggx, sums, NN);
    bn_finalize2_kernel<<<dim3(1, 2), 64, 0, stream>>>(sums, 64, invN,
                                                       g2c, g2s, be2c, be2s, bnscale, bnshift);

    // ---- Pool (BN+ReLU fused) ----
    pool2_kernel<<<dim3(NG, 2), 64, 0, stream>>>(aggx, bnscale, bnshift, batch, Hmean, NN);

    // ---- Head ----
    head_gemm1_kernel<<<NG, 64, 0, stream>>>(Hmean, Wf1, T);
    hipMemsetAsync(hsums, 0, 128 * 4, stream);
    bn_stats_kernel<64><<<32, 256, 0, stream>>>(T, NG, hsums);
    bn_finalize_kernel<<<1, 64, 0, stream>>>(hsums, 64, 1.0f / (float)NG, gf1, bef1,
                                             bnscale, bnshift);
    head_final_kernel<<<NG, 64, 0, stream>>>(T, bnscale, bnshift, Wf2, bf2, out);
}